// Round 1
// baseline (1578.735 us; speedup 1.0000x reference)
//
#include <hip/hip_runtime.h>
#include <math.h>

#define BATCH 16
#define HWPIX 36864      // 192*192
#define CCH 128
#define NCACHE 5
#define SCALE 0.125f
#define THRESH 0.7f
#define EPSV 1e-8f

typedef _Float16 f16;
typedef __attribute__((ext_vector_type(8))) _Float16 f16x8;
typedef __attribute__((ext_vector_type(4))) float f32x4;

__device__ __forceinline__ float psum8(float v) {
  v += __shfl_xor(v, 1);
  v += __shfl_xor(v, 2);
  v += __shfl_xor(v, 4);
  return v;
}

// ---------------- kpre1: M1, M2, M12 (fp32) + canonical-f16 M12, Q, W2 ----------------
// canonical B-operand layout for mfma_f32_16x16x32_f16:
//   idx = ((k>>3)*128 + n)*8 + (k&7)   (lane reads 8 contiguous f16 = b128)
// grid = 8 blocks, each handles a 2048-element slice of the 16384-element outputs.
__global__ __launch_bounds__(256) void kpre1(
    const float* __restrict__ A1, const float* __restrict__ B1,
    const float* __restrict__ A2, const float* __restrict__ B2,
    const float* __restrict__ W1, const float* __restrict__ W2,
    const float* __restrict__ cache_w,
    float* __restrict__ M1f, float* __restrict__ M12f,
    f16* __restrict__ M12h, f16* __restrict__ Qh, f16* __restrict__ W2h) {
  __shared__ float M1s[128 * 16];
  __shared__ float M2s[16 * 128];
  int t = threadIdx.x;
  int blk = blockIdx.x;  // 0..7
  for (int idx = t; idx < 2048; idx += 256) {
    int i = idx >> 4, r = idx & 15;
    float s = 0.f;
    for (int k = 0; k < 8; ++k) s += A1[i * 8 + k] * B1[k * 16 + r];
    s *= SCALE;
    M1s[idx] = s;
    if (blk == 0) M1f[idx] = s;
  }
  for (int idx = t; idx < 2048; idx += 256) {
    int r = idx >> 7, j = idx & 127;
    float s = 0.f;
    for (int k = 0; k < 8; ++k) s += A2[r * 8 + k] * B2[k * 128 + j];
    M2s[idx] = s * SCALE;
  }
  __syncthreads();
  for (int idx = blk * 2048 + t; idx < blk * 2048 + 2048; idx += 256) {
    int i = idx >> 7, j = idx & 127;
    float s = 0.f;
    for (int r = 0; r < 16; ++r) s += M1s[i * 16 + r] * M2s[r * 128 + j];
    M12f[idx] = s;
    M12h[(((i >> 3) * 128 + j) << 3) + (i & 7)] = (f16)s;
  }
  float cw = 1.f / (1.f + __expf(-cache_w[0]));
  float qs = 1.f - cw;
  for (int idx = blk * 2048 + t; idx < blk * 2048 + 2048; idx += 256) {
    int k = idx >> 7, n = idx & 127;
    int ci = (((k >> 3) * 128 + n) << 3) + (k & 7);
    Qh[ci] = (f16)(qs * W1[k * 128 + n]);
    W2h[ci] = (f16)W2[k * 128 + n];
  }
}

// ---------------- kpre2: P = cw*(M12@W1a) + M1@W1b, canonical f16 ----------------
__global__ __launch_bounds__(256) void kpre2(
    const float* __restrict__ W1, const float* __restrict__ M1f,
    const float* __restrict__ M12f, const float* __restrict__ cache_w,
    f16* __restrict__ Ph) {
  int t = threadIdx.x;
  int k = blockIdx.x * 8 + (t >> 5);
  int n0 = (t & 31) * 4;
  float cw = 1.f / (1.f + __expf(-cache_w[0]));
  float sa[4] = {0, 0, 0, 0}, sb[4] = {0, 0, 0, 0};
  for (int tt = 0; tt < 128; ++tt) {
    float m = M12f[k * 128 + tt];
    const float* wr = &W1[tt * 128 + n0];
    sa[0] += m * wr[0]; sa[1] += m * wr[1]; sa[2] += m * wr[2]; sa[3] += m * wr[3];
  }
  for (int r = 0; r < 16; ++r) {
    float m = M1f[k * 16 + r];
    const float* wr = &W1[(128 + r) * 128 + n0];
    sb[0] += m * wr[0]; sb[1] += m * wr[1]; sb[2] += m * wr[2]; sb[3] += m * wr[3];
  }
  for (int u = 0; u < 4; ++u) {
    int n = n0 + u;
    Ph[(((k >> 3) * 128 + n) << 3) + (k & 7)] = (f16)(cw * sa[u] + sb[u]);
  }
}

// ---------------- k2: x_lora = x@M12 (MFMA, direct-global A/B), out + num/xn2/cn2 ----------------
// LDS = double-buffered XLb only (33 KB). 1 barrier per g. B-frags read from L2.
__global__ __launch_bounds__(256, 4) void k2(
    const float* __restrict__ x, const float* __restrict__ cache,
    const f16* __restrict__ M12h, float* __restrict__ out,
    float* __restrict__ num, float* __restrict__ xn2, float* __restrict__ cn2) {
  __shared__ f16 XLb[2][64 * 132];   // x_lora tile, padded stride, double-buffered
  int t = threadIdx.x;
  int chunk = blockIdx.x;   // 0..575
  int grp = blockIdx.y;     // 0..3
  long pb = (long)chunk * 64;
  int lane = t & 63, w = t >> 6, l15 = lane & 15, q = lane >> 4;
  int arow = w * 16 + l15;           // pixel row within the 64-pixel tile (GEMM mapping)
  const uint4* Bf = (const uint4*)M12h;
  int part = t & 7;                  // sim mapping: 8-pixel slice
  int c0 = (t >> 3) * 4;             // sim mapping: 4-channel group

  // --- cn2 pre-pass (grp 0 only): per-channel cache norms; also warms L2 ---
  if (grp == 0) {
    f32x4 sc[5];
#pragma unroll
    for (int n = 0; n < 5; ++n) sc[n] = 0;
    const float* cp0 = cache + pb * CCH + c0;
#pragma unroll
    for (int pp = 0; pp < 8; ++pp) {
      int p = part * 8 + pp;
      const float* cp = cp0 + (long)p * CCH;
#pragma unroll
      for (int n = 0; n < 5; ++n) {
        f32x4 cv = *(const f32x4*)(cp + (long)n * HWPIX * CCH);
        sc[n] += cv * cv;
      }
    }
#pragma unroll
    for (int n = 0; n < 5; ++n)
#pragma unroll
      for (int j = 0; j < 4; ++j) {
        float v = psum8(sc[n][j]);
        if (part == 0) atomicAdd(&cn2[n * 128 + c0 + j], v);
      }
  }

  for (int g = 0; g < 4; ++g) {
    int b = grp * 4 + g;
    const float* xb = x + ((long)b * HWPIX + pb) * CCH;
    f16* xl_s = XLb[g & 1];
    // ---- GEMM: A (x) direct from global, B (M12h canonical) direct from L2 ----
    f32x4 acc[8];
#pragma unroll
    for (int ni = 0; ni < 8; ++ni) acc[ni] = 0;
#pragma unroll
    for (int kk = 0; kk < 4; ++kk) {
      const float* ap = xb + arow * CCH + kk * 32 + q * 8;
      f32x4 a0 = *(const f32x4*)ap;
      f32x4 a1 = *(const f32x4*)(ap + 4);
      f16x8 a;
      a[0] = (f16)a0[0]; a[1] = (f16)a0[1]; a[2] = (f16)a0[2]; a[3] = (f16)a0[3];
      a[4] = (f16)a1[0]; a[5] = (f16)a1[1]; a[6] = (f16)a1[2]; a[7] = (f16)a1[3];
#pragma unroll
      for (int ni = 0; ni < 8; ++ni) {
        uint4 bw = Bf[(kk * 4 + q) * 128 + ni * 16 + l15];
        acc[ni] = __builtin_amdgcn_mfma_f32_16x16x32_f16(a, *(const f16x8*)&bw,
                                                         acc[ni], 0, 0, 0);
      }
    }
    // ---- epilogue: out (fp32) + XLb (f16) ----
    float* ob = out + ((long)b * HWPIX + pb) * CCH;
#pragma unroll
    for (int ni = 0; ni < 8; ++ni) {
      int c = ni * 16 + l15;
#pragma unroll
      for (int r = 0; r < 4; ++r) {
        int p = w * 16 + q * 4 + r;
        float v = acc[ni][r];
        ob[(long)p * CCH + c] = v;
        xl_s[p * 132 + c] = (f16)v;
      }
    }
    __syncthreads();
    // ---- sim: thread = (4-channel group, 8-pixel slice); float4 cache loads ----
    f32x4 sn[5], s2;
#pragma unroll
    for (int n = 0; n < 5; ++n) sn[n] = 0;
    s2 = 0;
    const float* cq0 = cache + pb * CCH + c0;
#pragma unroll
    for (int pp = 0; pp < 8; ++pp) {
      int p = part * 8 + pp;
      const f16* xr = &xl_s[p * 132 + c0];
      f32x4 xv;
      xv[0] = (float)xr[0]; xv[1] = (float)xr[1];
      xv[2] = (float)xr[2]; xv[3] = (float)xr[3];
      const float* cp = cq0 + (long)p * CCH;
#pragma unroll
      for (int n = 0; n < 5; ++n) {
        f32x4 cv = *(const f32x4*)(cp + (long)n * HWPIX * CCH);
        sn[n] += xv * cv;
      }
      s2 += xv * xv;
    }
    // reduce over the 8 pixel-slices (lanes xor 1,2,4), flush once per (b,c)
#pragma unroll
    for (int n = 0; n < 5; ++n)
#pragma unroll
      for (int j = 0; j < 4; ++j) {
        float v = psum8(sn[n][j]);
        if (part == 0) atomicAdd(&num[((long)b * 5 + n) * 128 + c0 + j], v);
      }
#pragma unroll
    for (int j = 0; j < 4; ++j) {
      float v = psum8(s2[j]);
      if (part == 0) atomicAdd(&xn2[b * 128 + c0 + j], v);
    }
    // no end-of-g barrier: XLb is double-buffered; g+1's barrier covers the WAR on g+2
  }
}

// ---------------- k3: sims -> best_idx, mask ----------------
__global__ __launch_bounds__(128) void k3(
    const float* __restrict__ num, const float* __restrict__ xn2v,
    const float* __restrict__ cn2v, int* __restrict__ stats) {
  __shared__ float sims[16][5];
  int t = threadIdx.x;
  if (t < 80) {
    int b = t / 5, n = t % 5;
    float s = 0.f;
    for (int c = 0; c < 128; ++c) {
      float xn = sqrtf(xn2v[b * 128 + c]);
      float cn = sqrtf(cn2v[n * 128 + c]);
      s += num[(b * 5 + n) * 128 + c] / (fmaxf(xn, EPSV) * fmaxf(cn, EPSV));
    }
    sims[b][n] = s * (1.f / 128.f);
  }
  __syncthreads();
  if (t < 16) {
    float bv = -1e30f;
    int bi = 0;
    for (int n = 0; n < 5; ++n) {
      float v = sims[t][n];
      if (v > bv) { bv = v; bi = n; }   // strict > keeps first max
    }
    stats[t] = bi;
    stats[16 + t] = (bv > THRESH) ? 1 : 0;
  }
}

// ---------------- k4: fused = silu(x@P + best@Q + b1)@W2 + b2, barrier-free ----------------
// A-operands direct from global; B-operands (Ph/Qh/W2h, 32 KB each) direct from L2.
// As holds only the silu intermediate, which is wave-local (each wave writes/reads
// its own 16 pixel rows) -> zero __syncthreads.
__global__ __launch_bounds__(256, 4) void k4(
    const float* __restrict__ x, const float* __restrict__ cache,
    const f16* __restrict__ Ph, const f16* __restrict__ Qh,
    const f16* __restrict__ W2h, const float* __restrict__ b1,
    const float* __restrict__ b2, const int* __restrict__ stats,
    float* __restrict__ out) {
  int b = blockIdx.y;
  if (!stats[16 + b]) return;
  __shared__ f16 As[16 * 64 * 8];   // 16 KB, silu intermediate (canonical A layout)
  int t = threadIdx.x;
  int bi = stats[b];
  long pb = (long)blockIdx.x * 64;
  const float* xb = x + ((long)b * HWPIX + pb) * CCH;
  const float* cb = cache + ((long)bi * HWPIX + pb) * CCH;
  int lane = t & 63, w = t >> 6, l15 = lane & 15, q = lane >> 4;
  int arow = w * 16 + l15;
  const uint4* Pf = (const uint4*)Ph;
  const uint4* Qf = (const uint4*)Qh;
  const uint4* Wf = (const uint4*)W2h;

  f32x4 acc[8];
#pragma unroll
  for (int ni = 0; ni < 8; ++ni) acc[ni] = 0;
  // gemm1: x @ P
#pragma unroll
  for (int kk = 0; kk < 4; ++kk) {
    const float* ap = xb + arow * CCH + kk * 32 + q * 8;
    f32x4 a0 = *(const f32x4*)ap;
    f32x4 a1 = *(const f32x4*)(ap + 4);
    f16x8 a;
    a[0] = (f16)a0[0]; a[1] = (f16)a0[1]; a[2] = (f16)a0[2]; a[3] = (f16)a0[3];
    a[4] = (f16)a1[0]; a[5] = (f16)a1[1]; a[6] = (f16)a1[2]; a[7] = (f16)a1[3];
#pragma unroll
    for (int ni = 0; ni < 8; ++ni) {
      uint4 bw = Pf[(kk * 4 + q) * 128 + ni * 16 + l15];
      acc[ni] = __builtin_amdgcn_mfma_f32_16x16x32_f16(a, *(const f16x8*)&bw,
                                                       acc[ni], 0, 0, 0);
    }
  }
  // gemm2: += best @ Q
#pragma unroll
  for (int kk = 0; kk < 4; ++kk) {
    const float* ap = cb + arow * CCH + kk * 32 + q * 8;
    f32x4 a0 = *(const f32x4*)ap;
    f32x4 a1 = *(const f32x4*)(ap + 4);
    f16x8 a;
    a[0] = (f16)a0[0]; a[1] = (f16)a0[1]; a[2] = (f16)a0[2]; a[3] = (f16)a0[3];
    a[4] = (f16)a1[0]; a[5] = (f16)a1[1]; a[6] = (f16)a1[2]; a[7] = (f16)a1[3];
#pragma unroll
    for (int ni = 0; ni < 8; ++ni) {
      uint4 bw = Qf[(kk * 4 + q) * 128 + ni * 16 + l15];
      acc[ni] = __builtin_amdgcn_mfma_f32_16x16x32_f16(a, *(const f16x8*)&bw,
                                                       acc[ni], 0, 0, 0);
    }
  }
  // silu(acc + b1) -> As (wave-local rows, no barrier needed)
#pragma unroll
  for (int ni = 0; ni < 8; ++ni) {
    int c = ni * 16 + l15;
    float b1v = b1[c];
#pragma unroll
    for (int r = 0; r < 4; ++r) {
      int p = w * 16 + q * 4 + r;
      float hv = acc[ni][r] + b1v;
      float sv = hv / (1.f + __expf(-hv));
      As[(((c >> 3) * 64 + p) << 3) + (c & 7)] = (f16)sv;
    }
  }
  // gemm3: silu @ W2
#pragma unroll
  for (int ni = 0; ni < 8; ++ni) acc[ni] = 0;
#pragma unroll
  for (int kk = 0; kk < 4; ++kk) {
    f16x8 a = *(const f16x8*)&As[((kk * 4 + q) * 64 + arow) << 3];
#pragma unroll
    for (int ni = 0; ni < 8; ++ni) {
      uint4 bw = Wf[(kk * 4 + q) * 128 + ni * 16 + l15];
      acc[ni] = __builtin_amdgcn_mfma_f32_16x16x32_f16(a, *(const f16x8*)&bw,
                                                       acc[ni], 0, 0, 0);
    }
  }
  float* ob = out + ((long)b * HWPIX + pb) * CCH;
#pragma unroll
  for (int ni = 0; ni < 8; ++ni) {
    int c = ni * 16 + l15;
    float b2v = b2[c];
#pragma unroll
    for (int r = 0; r < 4; ++r) {
      int p = w * 16 + q * 4 + r;
      ob[(long)p * CCH + c] = acc[ni][r] + b2v;
    }
  }
}

// ---------------- launch ----------------
extern "C" void kernel_launch(void* const* d_in, const int* in_sizes, int n_in,
                              void* d_out, int out_size, void* d_ws, size_t ws_size,
                              hipStream_t stream) {
  const float* x  = (const float*)d_in[0];
  const float* A1 = (const float*)d_in[1];
  const float* B1 = (const float*)d_in[2];
  const float* A2 = (const float*)d_in[3];
  const float* B2 = (const float*)d_in[4];
  const float* W1 = (const float*)d_in[5];
  const float* b1 = (const float*)d_in[6];
  const float* W2 = (const float*)d_in[7];
  const float* b2 = (const float*)d_in[8];
  const float* cache_w = (const float*)d_in[9];
  const float* cache   = (const float*)d_in[10];
  float* out = (float*)d_out;
  char* wsb = (char*)d_ws;
  float* num  = (float*)(wsb + 0);       // 16*5*128 f
  float* xn2  = (float*)(wsb + 40960);   // 16*128 f
  float* cn2  = (float*)(wsb + 49152);   // 5*128 f
  int*   stats= (int*)  (wsb + 51712);   // best_idx[16], mask[16]
  float* M1f  = (float*)(wsb + 51840);   // 128*16 f
  float* M12f = (float*)(wsb + 60032);   // 128*128 f
  f16*   M12h = (f16*)  (wsb + 125568);  // canonical f16, 32KB each
  f16*   Ph   = (f16*)  (wsb + 158336);
  f16*   Qh   = (f16*)  (wsb + 191104);
  f16*   W2h  = (f16*)  (wsb + 223872);

  hipMemsetAsync(wsb, 0, 51712, stream);  // zero num/xn2/cn2
  kpre1<<<8, 256, 0, stream>>>(A1, B1, A2, B2, W1, W2, cache_w, M1f, M12f, M12h, Qh, W2h);
  kpre2<<<16, 256, 0, stream>>>(W1, M1f, M12f, cache_w, Ph);
  k2<<<dim3(576, 4), 256, 0, stream>>>(x, cache, M12h, out, num, xn2, cn2);
  k3<<<1, 128, 0, stream>>>(num, xn2, cn2, stats);
  k4<<<dim3(576, 16), 256, 0, stream>>>(x, cache, Ph, Qh, W2h, b1, b2, stats, out);
}

// Round 2
// 886.218 us; speedup vs baseline: 1.7814x; 1.7814x over previous
//
#include <hip/hip_runtime.h>
#include <math.h>

#define BATCH 16
#define HWPIX 36864      // 192*192
#define CCH 128
#define NCACHE 5
#define SCALE 0.125f
#define THRESH 0.7f
#define EPSV 1e-8f

typedef _Float16 f16;
typedef __attribute__((ext_vector_type(8))) _Float16 f16x8;
typedef __attribute__((ext_vector_type(4))) float f32x4;

// ---------------- kpre1: M1, M2, M12 (fp32) + canonical-f16 M12, Q, W2 ----------------
// canonical B-operand layout for mfma_f32_16x16x32_f16:
//   idx = ((k>>3)*128 + n)*8 + (k&7)   (lane reads 8 contiguous f16 = b128)
__global__ __launch_bounds__(256) void kpre1(
    const float* __restrict__ A1, const float* __restrict__ B1,
    const float* __restrict__ A2, const float* __restrict__ B2,
    const float* __restrict__ W1, const float* __restrict__ W2,
    const float* __restrict__ cache_w,
    float* __restrict__ M1f, float* __restrict__ M12f,
    f16* __restrict__ M12h, f16* __restrict__ Qh, f16* __restrict__ W2h) {
  __shared__ float M1s[128 * 16];
  __shared__ float M2s[16 * 128];
  int t = threadIdx.x;
  int blk = blockIdx.x;  // 0..7
  for (int idx = t; idx < 2048; idx += 256) {
    int i = idx >> 4, r = idx & 15;
    float s = 0.f;
    for (int k = 0; k < 8; ++k) s += A1[i * 8 + k] * B1[k * 16 + r];
    s *= SCALE;
    M1s[idx] = s;
    if (blk == 0) M1f[idx] = s;
  }
  for (int idx = t; idx < 2048; idx += 256) {
    int r = idx >> 7, j = idx & 127;
    float s = 0.f;
    for (int k = 0; k < 8; ++k) s += A2[r * 8 + k] * B2[k * 128 + j];
    M2s[idx] = s * SCALE;
  }
  __syncthreads();
  for (int idx = blk * 2048 + t; idx < blk * 2048 + 2048; idx += 256) {
    int i = idx >> 7, j = idx & 127;
    float s = 0.f;
    for (int r = 0; r < 16; ++r) s += M1s[i * 16 + r] * M2s[r * 128 + j];
    M12f[idx] = s;
    M12h[(((i >> 3) * 128 + j) << 3) + (i & 7)] = (f16)s;
  }
  float cw = 1.f / (1.f + __expf(-cache_w[0]));
  float qs = 1.f - cw;
  for (int idx = blk * 2048 + t; idx < blk * 2048 + 2048; idx += 256) {
    int k = idx >> 7, n = idx & 127;
    int ci = (((k >> 3) * 128 + n) << 3) + (k & 7);
    Qh[ci] = (f16)(qs * W1[k * 128 + n]);
    W2h[ci] = (f16)W2[k * 128 + n];
  }
}

// ---------------- kpre2: P = cw*(M12@W1a) + M1@W1b, canonical f16 ----------------
__global__ __launch_bounds__(256) void kpre2(
    const float* __restrict__ W1, const float* __restrict__ M1f,
    const float* __restrict__ M12f, const float* __restrict__ cache_w,
    f16* __restrict__ Ph) {
  int t = threadIdx.x;
  int k = blockIdx.x * 8 + (t >> 5);
  int n0 = (t & 31) * 4;
  float cw = 1.f / (1.f + __expf(-cache_w[0]));
  float sa[4] = {0, 0, 0, 0}, sb[4] = {0, 0, 0, 0};
  for (int tt = 0; tt < 128; ++tt) {
    float m = M12f[k * 128 + tt];
    const float* wr = &W1[tt * 128 + n0];
    sa[0] += m * wr[0]; sa[1] += m * wr[1]; sa[2] += m * wr[2]; sa[3] += m * wr[3];
  }
  for (int r = 0; r < 16; ++r) {
    float m = M1f[k * 16 + r];
    const float* wr = &W1[(128 + r) * 128 + n0];
    sb[0] += m * wr[0]; sb[1] += m * wr[1]; sb[2] += m * wr[2]; sb[3] += m * wr[3];
  }
  for (int u = 0; u < 4; ++u) {
    int n = n0 + u;
    Ph[(((k >> 3) * 128 + n) << 3) + (k & 7)] = (f16)(cw * sa[u] + sb[u]);
  }
}

// ---------------- k2: x_lora = x@M12 (MFMA), out + num/xn2/cn2 ----------------
// Round-0 traffic structure (grp=2, 8 batches/block, Bs LDS-staged, sim lanes =
// consecutive channels) with occupancy fixes: A direct from global (no As LDS),
// sim partials in registers (no nacc LDS). LDS 49 KB -> 3 blocks/CU, 2 barriers/g.
__global__ __launch_bounds__(256, 3) void k2(
    const float* __restrict__ x, const float* __restrict__ cache,
    const f16* __restrict__ M12h, float* __restrict__ out,
    float* __restrict__ num, float* __restrict__ xn2, float* __restrict__ cn2) {
  __shared__ f16 Bs[16 * 128 * 8];   // 32 KB: M12 canonical
  __shared__ f16 XLb[64 * 132];      // 16.9 KB: x_lora tile, padded stride
  int t = threadIdx.x;
  int chunk = blockIdx.x;   // 0..575
  int grp = blockIdx.y;     // 0..1
  long pb = (long)chunk * 64;
  {
    const uint4* src = (const uint4*)M12h;
    uint4* dst = (uint4*)Bs;
    for (int i = t; i < 2048; i += 256) dst[i] = src[i];
  }
  int lane = t & 63, w = t >> 6, l15 = lane & 15, q = lane >> 4;
  int arow = w * 16 + l15;        // pixel row within the 64-pixel tile
  int c = t & 127;                // sim: channel (lanes consecutive -> 256B rows)
  bool hi = t >= 128;             // sim: lo handles n0..2, hi handles n3..4 + s2
  __syncthreads();                // Bs ready

  for (int g = 0; g < 8; ++g) {
    int b = grp * 8 + g;
    const float* xb = x + ((long)b * HWPIX + pb) * CCH;
    // ---- GEMM: A (x) direct from global fp32->f16, B from LDS ----
    f32x4 acc[8];
#pragma unroll
    for (int ni = 0; ni < 8; ++ni) acc[ni] = 0;
#pragma unroll
    for (int kk = 0; kk < 4; ++kk) {
      const float* ap = xb + arow * CCH + kk * 32 + q * 8;
      f32x4 a0 = *(const f32x4*)ap;
      f32x4 a1 = *(const f32x4*)(ap + 4);
      f16x8 a;
      a[0] = (f16)a0[0]; a[1] = (f16)a0[1]; a[2] = (f16)a0[2]; a[3] = (f16)a0[3];
      a[4] = (f16)a1[0]; a[5] = (f16)a1[1]; a[6] = (f16)a1[2]; a[7] = (f16)a1[3];
#pragma unroll
      for (int ni = 0; ni < 8; ++ni) {
        f16x8 bb = *(const f16x8*)&Bs[(((kk * 4 + q) * 128 + ni * 16 + l15)) << 3];
        acc[ni] = __builtin_amdgcn_mfma_f32_16x16x32_f16(a, bb, acc[ni], 0, 0, 0);
      }
    }
    __syncthreads();   // prev sim done reading XLb (no-op for g=0)
    // ---- epilogue: out (fp32) + XLb (f16) ----
    float* ob = out + ((long)b * HWPIX + pb) * CCH;
#pragma unroll
    for (int ni = 0; ni < 8; ++ni) {
      int cc = ni * 16 + l15;
#pragma unroll
      for (int r = 0; r < 4; ++r) {
        int p = w * 16 + q * 4 + r;
        float v = acc[ni][r];
        ob[(long)p * CCH + cc] = v;
        XLb[p * 132 + cc] = (f16)v;
      }
    }
    __syncthreads();   // XLb ready
    // ---- sim: thread = channel; lo: n0..2, hi: n3..4 + xn2; register partials ----
    {
      bool docn = (grp == 0) && (g == 0);
      const float* cb = cache + pb * CCH + c;
      float s0 = 0, s1 = 0, s2v = 0;          // lo: num0,1,2 | hi: num3,4,xn2
      float q0 = 0, q1 = 0, q2 = 0;           // cn2 partials (docn only)
      if (!hi) {
#pragma unroll 4
        for (int p = 0; p < 64; ++p) {
          float xl = (float)XLb[p * 132 + c];
          float cv0 = cb[((long)0 * HWPIX + p) * CCH];
          float cv1 = cb[((long)1 * HWPIX + p) * CCH];
          float cv2 = cb[((long)2 * HWPIX + p) * CCH];
          s0 += xl * cv0; s1 += xl * cv1; s2v += xl * cv2;
          if (docn) { q0 += cv0 * cv0; q1 += cv1 * cv1; q2 += cv2 * cv2; }
        }
        atomicAdd(&num[((long)b * 5 + 0) * 128 + c], s0);
        atomicAdd(&num[((long)b * 5 + 1) * 128 + c], s1);
        atomicAdd(&num[((long)b * 5 + 2) * 128 + c], s2v);
        if (docn) {
          atomicAdd(&cn2[0 * 128 + c], q0);
          atomicAdd(&cn2[1 * 128 + c], q1);
          atomicAdd(&cn2[2 * 128 + c], q2);
        }
      } else {
#pragma unroll 4
        for (int p = 0; p < 64; ++p) {
          float xl = (float)XLb[p * 132 + c];
          float cv3 = cb[((long)3 * HWPIX + p) * CCH];
          float cv4 = cb[((long)4 * HWPIX + p) * CCH];
          s0 += xl * cv3; s1 += xl * cv4; s2v += xl * xl;
          if (docn) { q0 += cv3 * cv3; q1 += cv4 * cv4; }
        }
        atomicAdd(&num[((long)b * 5 + 3) * 128 + c], s0);
        atomicAdd(&num[((long)b * 5 + 4) * 128 + c], s1);
        atomicAdd(&xn2[b * 128 + c], s2v);
        if (docn) {
          atomicAdd(&cn2[3 * 128 + c], q0);
          atomicAdd(&cn2[4 * 128 + c], q1);
        }
      }
    }
    // next g's gemm reads only global/Bs; sync before XLb overwrite is the one above
  }
}

// ---------------- k3: sims -> best_idx, mask ----------------
__global__ __launch_bounds__(128) void k3(
    const float* __restrict__ num, const float* __restrict__ xn2v,
    const float* __restrict__ cn2v, int* __restrict__ stats) {
  __shared__ float sims[16][5];
  int t = threadIdx.x;
  if (t < 80) {
    int b = t / 5, n = t % 5;
    float s = 0.f;
    for (int c = 0; c < 128; ++c) {
      float xn = sqrtf(xn2v[b * 128 + c]);
      float cn = sqrtf(cn2v[n * 128 + c]);
      s += num[(b * 5 + n) * 128 + c] / (fmaxf(xn, EPSV) * fmaxf(cn, EPSV));
    }
    sims[b][n] = s * (1.f / 128.f);
  }
  __syncthreads();
  if (t < 16) {
    float bv = -1e30f;
    int bi = 0;
    for (int n = 0; n < 5; ++n) {
      float v = sims[t][n];
      if (v > bv) { bv = v; bi = n; }   // strict > keeps first max
    }
    stats[t] = bi;
    stats[16 + t] = (bv > THRESH) ? 1 : 0;
  }
}

// ---------------- k4: fused = silu(x@P + best@Q + b1)@W2 + b2, barrier-free ----------------
// A-operands direct from global; B-operands (Ph/Qh/W2h, 32 KB each) direct from L2.
// As holds only the silu intermediate, which is wave-local -> zero __syncthreads.
__global__ __launch_bounds__(256, 4) void k4(
    const float* __restrict__ x, const float* __restrict__ cache,
    const f16* __restrict__ Ph, const f16* __restrict__ Qh,
    const f16* __restrict__ W2h, const float* __restrict__ b1,
    const float* __restrict__ b2, const int* __restrict__ stats,
    float* __restrict__ out) {
  int b = blockIdx.y;
  if (!stats[16 + b]) return;
  __shared__ f16 As[16 * 64 * 8];   // 16 KB, silu intermediate (canonical A layout)
  int t = threadIdx.x;
  int bi = stats[b];
  long pb = (long)blockIdx.x * 64;
  const float* xb = x + ((long)b * HWPIX + pb) * CCH;
  const float* cb = cache + ((long)bi * HWPIX + pb) * CCH;
  int lane = t & 63, w = t >> 6, l15 = lane & 15, q = lane >> 4;
  int arow = w * 16 + l15;
  const uint4* Pf = (const uint4*)Ph;
  const uint4* Qf = (const uint4*)Qh;
  const uint4* Wf = (const uint4*)W2h;

  f32x4 acc[8];
#pragma unroll
  for (int ni = 0; ni < 8; ++ni) acc[ni] = 0;
  // gemm1: x @ P
#pragma unroll
  for (int kk = 0; kk < 4; ++kk) {
    const float* ap = xb + arow * CCH + kk * 32 + q * 8;
    f32x4 a0 = *(const f32x4*)ap;
    f32x4 a1 = *(const f32x4*)(ap + 4);
    f16x8 a;
    a[0] = (f16)a0[0]; a[1] = (f16)a0[1]; a[2] = (f16)a0[2]; a[3] = (f16)a0[3];
    a[4] = (f16)a1[0]; a[5] = (f16)a1[1]; a[6] = (f16)a1[2]; a[7] = (f16)a1[3];
#pragma unroll
    for (int ni = 0; ni < 8; ++ni) {
      uint4 bw = Pf[(kk * 4 + q) * 128 + ni * 16 + l15];
      acc[ni] = __builtin_amdgcn_mfma_f32_16x16x32_f16(a, *(const f16x8*)&bw,
                                                       acc[ni], 0, 0, 0);
    }
  }
  // gemm2: += best @ Q
#pragma unroll
  for (int kk = 0; kk < 4; ++kk) {
    const float* ap = cb + arow * CCH + kk * 32 + q * 8;
    f32x4 a0 = *(const f32x4*)ap;
    f32x4 a1 = *(const f32x4*)(ap + 4);
    f16x8 a;
    a[0] = (f16)a0[0]; a[1] = (f16)a0[1]; a[2] = (f16)a0[2]; a[3] = (f16)a0[3];
    a[4] = (f16)a1[0]; a[5] = (f16)a1[1]; a[6] = (f16)a1[2]; a[7] = (f16)a1[3];
#pragma unroll
    for (int ni = 0; ni < 8; ++ni) {
      uint4 bw = Qf[(kk * 4 + q) * 128 + ni * 16 + l15];
      acc[ni] = __builtin_amdgcn_mfma_f32_16x16x32_f16(a, *(const f16x8*)&bw,
                                                       acc[ni], 0, 0, 0);
    }
  }
  // silu(acc + b1) -> As (wave-local rows, no barrier needed)
#pragma unroll
  for (int ni = 0; ni < 8; ++ni) {
    int cc = ni * 16 + l15;
    float b1v = b1[cc];
#pragma unroll
    for (int r = 0; r < 4; ++r) {
      int p = w * 16 + q * 4 + r;
      float hv = acc[ni][r] + b1v;
      float sv = hv / (1.f + __expf(-hv));
      As[(((cc >> 3) * 64 + p) << 3) + (cc & 7)] = (f16)sv;
    }
  }
  // gemm3: silu @ W2
#pragma unroll
  for (int ni = 0; ni < 8; ++ni) acc[ni] = 0;
#pragma unroll
  for (int kk = 0; kk < 4; ++kk) {
    f16x8 a = *(const f16x8*)&As[((kk * 4 + q) * 64 + arow) << 3];
#pragma unroll
    for (int ni = 0; ni < 8; ++ni) {
      uint4 bw = Wf[(kk * 4 + q) * 128 + ni * 16 + l15];
      acc[ni] = __builtin_amdgcn_mfma_f32_16x16x32_f16(a, *(const f16x8*)&bw,
                                                       acc[ni], 0, 0, 0);
    }
  }
  float* ob = out + ((long)b * HWPIX + pb) * CCH;
#pragma unroll
  for (int ni = 0; ni < 8; ++ni) {
    int cc = ni * 16 + l15;
    float b2v = b2[cc];
#pragma unroll
    for (int r = 0; r < 4; ++r) {
      int p = w * 16 + q * 4 + r;
      ob[(long)p * CCH + cc] = acc[ni][r] + b2v;
    }
  }
}

// ---------------- launch ----------------
extern "C" void kernel_launch(void* const* d_in, const int* in_sizes, int n_in,
                              void* d_out, int out_size, void* d_ws, size_t ws_size,
                              hipStream_t stream) {
  const float* x  = (const float*)d_in[0];
  const float* A1 = (const float*)d_in[1];
  const float* B1 = (const float*)d_in[2];
  const float* A2 = (const float*)d_in[3];
  const float* B2 = (const float*)d_in[4];
  const float* W1 = (const float*)d_in[5];
  const float* b1 = (const float*)d_in[6];
  const float* W2 = (const float*)d_in[7];
  const float* b2 = (const float*)d_in[8];
  const float* cache_w = (const float*)d_in[9];
  const float* cache   = (const float*)d_in[10];
  float* out = (float*)d_out;
  char* wsb = (char*)d_ws;
  float* num  = (float*)(wsb + 0);       // 16*5*128 f
  float* xn2  = (float*)(wsb + 40960);   // 16*128 f
  float* cn2  = (float*)(wsb + 49152);   // 5*128 f
  int*   stats= (int*)  (wsb + 51712);   // best_idx[16], mask[16]
  float* M1f  = (float*)(wsb + 51840);   // 128*16 f
  float* M12f = (float*)(wsb + 60032);   // 128*128 f
  f16*   M12h = (f16*)  (wsb + 125568);  // canonical f16, 32KB each
  f16*   Ph   = (f16*)  (wsb + 158336);
  f16*   Qh   = (f16*)  (wsb + 191104);
  f16*   W2h  = (f16*)  (wsb + 223872);

  hipMemsetAsync(wsb, 0, 51712, stream);  // zero num/xn2/cn2
  kpre1<<<8, 256, 0, stream>>>(A1, B1, A2, B2, W1, W2, cache_w, M1f, M12f, M12h, Qh, W2h);
  kpre2<<<16, 256, 0, stream>>>(W1, M1f, M12f, cache_w, Ph);
  k2<<<dim3(576, 2), 256, 0, stream>>>(x, cache, M12h, out, num, xn2, cn2);
  k3<<<1, 128, 0, stream>>>(num, xn2, cn2, stats);
  k4<<<dim3(576, 16), 256, 0, stream>>>(x, cache, Ph, Qh, W2h, b1, b2, stats, out);
}